// Round 12
// baseline (1645.761 us; speedup 1.0000x reference)
//
#include <hip/hip_runtime.h>
#include <hip/hip_bf16.h>
#include <math.h>

// MEASUREMENT ROUND: every phase kernel repeats its full work REP times inside
// one launch so each phase exceeds the 115us harness fills and surfaces in the
// top-5 rocprof table with its counters. Semantics preserved (idempotent regs /
// per-iteration cursor+bco epochs for the scatter). dur/8 = true phase time.

#define NFEAT 512
#define NCLS  40
#define NBUCK_MAX 512          // buckets = ceil(N/256); N=100000 -> 391
#define CAP   9728             // bucket capacity: mean 8192 + ~17 sigma
#define REP   8

typedef __attribute__((ext_vector_type(8))) short bf16x8;
typedef __attribute__((ext_vector_type(4))) float f32x4;

__device__ inline short f2bf(float f) {
    union { float f; unsigned u; } v; v.f = f;
    unsigned r = (v.u + 0x7FFFu + ((v.u >> 16) & 1u)) >> 16;   // RNE
    return (short)r;
}
__device__ inline float bf2f(unsigned short u) {
    union { unsigned u; float f; } r; r.u = (unsigned)u << 16; return r.f;
}

// ---- 1. radix partition, REP epochs (separate cursor+bco per epoch) ------

__global__ __launch_bounds__(256) void scat7_kernel(const int* __restrict__ src,
                                                    const int* __restrict__ dst,
                                                    int* __restrict__ bcursor_all,
                                                    unsigned* __restrict__ bco_all,
                                                    int E, int nbuck) {
    __shared__ int h[NBUCK_MAX], h2[NBUCK_MAX], base[NBUCK_MAX];
    int t = threadIdx.x;
    int cb = blockIdx.x * 2048;
    int d[8], s[8];
    bool m[8];
    #pragma unroll
    for (int u = 0; u < 8; ++u) {
        int e = cb + u * 256 + t;
        m[u] = e < E;
        d[u] = m[u] ? __builtin_nontemporal_load(dst + e) : 0;
        s[u] = m[u] ? __builtin_nontemporal_load(src + e) : 0;
    }
    for (int it = 0; it < REP; ++it) {
        int*      bcur = bcursor_all + it * NBUCK_MAX;
        unsigned* bco  = bco_all + (size_t)it * nbuck * CAP;
        h[t] = 0; h[t + 256] = 0; h2[t] = 0; h2[t + 256] = 0;
        __syncthreads();
        #pragma unroll
        for (int u = 0; u < 8; ++u)
            if (m[u]) atomicAdd(&h[d[u] >> 8], 1);
        __syncthreads();
        #pragma unroll
        for (int b = 0; b < 2; ++b) {
            int bb = t + b * 256;
            if (h[bb]) base[bb] = bb * CAP + atomicAdd(&bcur[bb], h[bb]);
        }
        __syncthreads();
        #pragma unroll
        for (int u = 0; u < 8; ++u) {
            if (m[u]) {
                int b = d[u] >> 8;
                int lp = atomicAdd(&h2[b], 1);
                bco[base[b] + lp] = ((unsigned)s[u] << 8) | (unsigned)(d[u] & 255);
            }
        }
        __syncthreads();
        asm volatile("" ::: "memory");
    }
}

// ---- 2. per-bucket counting sort (idempotent, REP loops) -----------------

__global__ __launch_bounds__(256) void sortb3_kernel(const unsigned* __restrict__ bco,
                                                     const int* __restrict__ bcursor,
                                                     int4* __restrict__ rowinfo,
                                                     float* __restrict__ dinv,
                                                     int* __restrict__ csr_src, int N) {
    __shared__ int deg[256], ex[256], sc[256];
    int b = blockIdx.x, t = threadIdx.x;
    int lo = b * 256;
    int nn = N - lo; if (nn > 256) nn = 256;
    int ebeg = b * CAP;
    int ecnt = bcursor[b];

    for (int it = 0; it < REP; ++it) {
        deg[t] = 0;
        __syncthreads();
        for (int i = t; i < ecnt; i += 256)
            atomicAdd(&deg[bco[ebeg + i] & 255u], 1);
        __syncthreads();
        int v = deg[t];
        sc[t] = v;
        __syncthreads();
        for (int off = 1; off < 256; off <<= 1) {
            int u = (t >= off) ? sc[t - off] : 0;
            __syncthreads();
            sc[t] += u;
            __syncthreads();
        }
        int ext = sc[t] - v;
        ex[t] = ext;
        if (t < nn) {
            float di = rsqrtf((float)(v + 1));          // +1 self-loop
            int4 ri;
            ri.x = ebeg + ext;
            ri.y = v;
            ri.z = __float_as_int(di);
            ri.w = 0;
            rowinfo[lo + t] = ri;
            dinv[lo + t]    = di;
        }
        __syncthreads();
        for (int i = t; i < ecnt; i += 256) {
            unsigned e = bco[ebeg + i];
            int p = atomicAdd(&ex[e & 255u], 1);
            csr_src[ebeg + p] = (int)(e >> 8);
        }
        __syncthreads();
        asm volatile("" ::: "memory");
    }
}

// ---- W -> MFMA fragment pack ---------------------------------------------

__global__ void wfrag_kernel(const float* __restrict__ W, short* __restrict__ wfrag) {
    int i = blockIdx.x * blockDim.x + threadIdx.x;
    if (i >= 16 * 3 * 64) return;
    int kc = i / 192, rem = i % 192, tile = rem / 64, lane = rem % 64;
    int c = tile * 16 + (lane & 15);
    int kbase = kc * 32 + ((lane >> 4) << 3);
    bf16x8 out;
    #pragma unroll
    for (int j = 0; j < 8; ++j) {
        float v = (c < NCLS) ? W[(size_t)c * NFEAT + kbase + j] : 0.f;
        out[j] = f2bf(v);
    }
    *(bf16x8*)(wfrag + (size_t)i * 8) = out;
}

// ---- z' = dinv . (x @ W^T), REP loops ------------------------------------

__global__ __launch_bounds__(512) void gemm5_kernel(const float* __restrict__ x,
                                                    const short* __restrict__ wfrag,
                                                    const float* __restrict__ dinv,
                                                    unsigned short* __restrict__ zb, int n) {
    __shared__ short xl[2][128 * 40];
    int t = threadIdx.x;
    int w = t >> 6, l = t & 63;
    int lrow = l & 15, lk = l >> 4;
    int rowBase = blockIdx.x * 128;
    int srow = t >> 2, skq = t & 3;
    const float* xrow = x + (size_t)(rowBase + srow) * NFEAT + skq * 8;
    bool srOK = (rowBase + srow) < n;
    int aoff = (w * 16 + lrow) * 40 + lk * 8;
    int doff = srow * 40 + skq * 8;

    for (int it = 0; it < REP; ++it) {
        f32x4 acc0 = {0.f, 0.f, 0.f, 0.f}, acc1 = acc0, acc2 = acc0;
        __syncthreads();                            // prev rep fully done
        {   // prologue: stage kc=0
            float4 v0 = make_float4(0.f, 0.f, 0.f, 0.f), v1 = v0;
            if (srOK) { const float4* xp = (const float4*)xrow; v0 = xp[0]; v1 = xp[1]; }
            bf16x8 bv;
            bv[0] = f2bf(v0.x); bv[1] = f2bf(v0.y); bv[2] = f2bf(v0.z); bv[3] = f2bf(v0.w);
            bv[4] = f2bf(v1.x); bv[5] = f2bf(v1.y); bv[6] = f2bf(v1.z); bv[7] = f2bf(v1.w);
            *(bf16x8*)&xl[0][doff] = bv;
        }
        __syncthreads();
        for (int kc = 0; kc < 16; ++kc) {
            int cur = kc & 1;
            float4 v0 = make_float4(0.f, 0.f, 0.f, 0.f), v1 = v0;
            if (kc < 15 && srOK) {
                const float4* xp = (const float4*)(xrow + (kc + 1) * 32);
                v0 = xp[0]; v1 = xp[1];
            }
            bf16x8 af = *(const bf16x8*)&xl[cur][aoff];
            const bf16x8* wf = (const bf16x8*)(wfrag + (size_t)kc * 3 * 64 * 8);
            bf16x8 b0 = wf[l];
            bf16x8 b1 = wf[64 + l];
            bf16x8 b2 = wf[128 + l];
            acc0 = __builtin_amdgcn_mfma_f32_16x16x32_bf16(af, b0, acc0, 0, 0, 0);
            acc1 = __builtin_amdgcn_mfma_f32_16x16x32_bf16(af, b1, acc1, 0, 0, 0);
            acc2 = __builtin_amdgcn_mfma_f32_16x16x32_bf16(af, b2, acc2, 0, 0, 0);
            if (kc < 15) {
                bf16x8 bv;
                bv[0] = f2bf(v0.x); bv[1] = f2bf(v0.y); bv[2] = f2bf(v0.z); bv[3] = f2bf(v0.w);
                bv[4] = f2bf(v1.x); bv[5] = f2bf(v1.y); bv[6] = f2bf(v1.z); bv[7] = f2bf(v1.w);
                *(bf16x8*)&xl[cur ^ 1][doff] = bv;
                __syncthreads();
            }
        }
        int r0 = rowBase + w * 16 + lk * 4;
        #pragma unroll
        for (int reg = 0; reg < 4; ++reg) {
            int row = r0 + reg;
            if (row < n) {
                float sc = dinv[row];
                unsigned short* zp = zb + (size_t)row * NCLS;
                zp[lrow]      = (unsigned short)f2bf(acc0[reg] * sc);
                zp[16 + lrow] = (unsigned short)f2bf(acc1[reg] * sc);
                if (lrow < 8) zp[32 + lrow] = (unsigned short)f2bf(acc2[reg] * sc);
            }
        }
        asm volatile("" ::: "memory");
    }
}

// ---- unweighted pull-SpMM, REP loops -------------------------------------

template <bool FINAL>
__global__ __launch_bounds__(256) void spmm6_kernel(const unsigned short* __restrict__ in,
                                                    const int4* __restrict__ rowinfo,
                                                    const int* __restrict__ csr,
                                                    const float* __restrict__ bias,
                                                    void* __restrict__ outv, int n) {
    int wv = (int)((blockIdx.x * (size_t)blockDim.x + threadIdx.x) >> 6);
    wv = __builtin_amdgcn_readfirstlane(wv);
    if (wv >= n) return;
    int lane = threadIdx.x & 63;
    bool lact = lane < NCLS;

    int4 ri = rowinfo[wv];
    int beg = ri.x, tot = ri.y;
    float dd = __int_as_float(ri.z);

    for (int it = 0; it < REP; ++it) {
        float a = lact ? bf2f(in[(size_t)wv * NCLS + lane]) : 0.f;
        int j = 0;
        for (; j + 4 <= tot; j += 4) {
            int s0 = csr[beg + j];
            int s1 = csr[beg + j + 1];
            int s2 = csr[beg + j + 2];
            int s3 = csr[beg + j + 3];
            if (lact) {
                float v0 = bf2f(in[(size_t)s0 * NCLS + lane]);
                float v1 = bf2f(in[(size_t)s1 * NCLS + lane]);
                float v2 = bf2f(in[(size_t)s2 * NCLS + lane]);
                float v3 = bf2f(in[(size_t)s3 * NCLS + lane]);
                a += v0; a += v1; a += v2; a += v3;
            }
        }
        for (; j < tot; ++j) {
            int s = csr[beg + j];
            if (lact) a += bf2f(in[(size_t)s * NCLS + lane]);
        }

        if (!FINAL) {
            if (lact) {
                unsigned short* ob = (unsigned short*)outv;
                ob[(size_t)wv * NCLS + lane] = (unsigned short)f2bf(a * dd * dd);
            }
        } else {
            float v = lact ? a * dd + bias[lane] : -INFINITY;
            float m = v;
            #pragma unroll
            for (int off = 32; off; off >>= 1) m = fmaxf(m, __shfl_xor(m, off, 64));
            float e = lact ? expf(v - m) : 0.f;
            float s = e;
            #pragma unroll
            for (int off = 32; off; off >>= 1) s += __shfl_xor(s, off, 64);
            float lse = logf(s);
            if (lact) {
                float* out = (float*)outv;
                out[(size_t)wv * NCLS + lane] = v - m - lse;
            }
        }
        asm volatile("" ::: "memory");
    }
}

// ---- driver -------------------------------------------------------------

extern "C" void kernel_launch(void* const* d_in, const int* in_sizes, int n_in,
                              void* d_out, int out_size, void* d_ws, size_t ws_size,
                              hipStream_t stream) {
    const float* x  = (const float*)d_in[0];
    const int*   ei = (const int*)d_in[1];
    const float* W  = (const float*)d_in[2];
    const float* b  = (const float*)d_in[3];

    const int N = in_sizes[0] / NFEAT;
    const int E = in_sizes[1] / 2;
    const int* src = ei;
    const int* dst = ei + E;
    const int nbuck = (N + 255) >> 8;      // 391

    char* p = (char*)d_ws;
    auto alloc = [&](size_t bytes) -> void* {
        void* r = (void*)p;
        p += (bytes + 255) & ~(size_t)255;
        return r;
    };
    int*      bcursor = (int*)     alloc((size_t)REP * NBUCK_MAX * 4);
    int4*     rowinfo = (int4*)    alloc((size_t)N * 16);
    float*    dinv    = (float*)   alloc((size_t)N * 4);
    unsigned* bco     = (unsigned*)alloc((size_t)REP * nbuck * CAP * 4 + 64);
    int*      csr_src = (int*)     alloc((size_t)nbuck * CAP * 4 + 64);
    short*    wfrag   = (short*)   alloc((size_t)16 * 3 * 64 * 8 * 2);
    unsigned short* zb = (unsigned short*)alloc((size_t)N * NCLS * 2 + 256);
    unsigned short* h1 = (unsigned short*)alloc((size_t)N * NCLS * 2 + 256);

    hipMemsetAsync(bcursor, 0, (size_t)REP * NBUCK_MAX * 4, stream);

    int cb = (E + 2047) / 2048;
    scat7_kernel<<<cb, 256, 0, stream>>>(src, dst, bcursor, bco, E, nbuck);
    // consume the LAST epoch's cursor + bco
    sortb3_kernel<<<nbuck, 256, 0, stream>>>(bco + (size_t)(REP - 1) * nbuck * CAP,
                                             bcursor + (REP - 1) * NBUCK_MAX,
                                             rowinfo, dinv, csr_src, N);

    wfrag_kernel<<<12, 256, 0, stream>>>(W, wfrag);
    gemm5_kernel<<<(N + 127) / 128, 512, 0, stream>>>(x, wfrag, dinv, zb, N);

    int wb = (int)(((size_t)N * 64 + 255) / 256);
    spmm6_kernel<false><<<wb, 256, 0, stream>>>(zb, rowinfo, csr_src, b, h1, N);
    spmm6_kernel<true ><<<wb, 256, 0, stream>>>(h1, rowinfo, csr_src, b, d_out, N);
}

// Round 13
// 343.087 us; speedup vs baseline: 4.7969x; 4.7969x over previous
//
#include <hip/hip_runtime.h>
#include <hip/hip_bf16.h>
#include <math.h>

// SGC: out = log_softmax( (A_norm^2 x) W^T + b )
// (A^2 x) W^T == A^2 (x W^T): propagate 40-dim. Weight factorization:
// z' = dinv.z; pass1 = dd^2*sum (bf16); pass2 = dd*sum + b -> log_softmax.
// SPLIT-PLANE feature layout (R13): plane A = classes 0..31, 64B-aligned rows
// -> exactly 1 cache line per edge gather (L3-BW-bound phase, R12 measured
// 12.4 TB/s ~ L3 ceiling); plane B = classes 32..39, 16B rows, 1.6MB buffer
// (L2-resident, 4 rows/line reuse). Halves L3 bytes of the dominant phase.
// CSR build: padded radix buckets of 256 nodes + counting sort (R11).

#define NFEAT 512
#define NCLS  40
#define NBUCK_MAX 512          // buckets = ceil(N/256); N=100000 -> 391
#define CAP   9728             // bucket capacity: mean 8192 + ~17 sigma

typedef __attribute__((ext_vector_type(8))) short bf16x8;
typedef __attribute__((ext_vector_type(4))) float f32x4;

__device__ inline short f2bf(float f) {
    union { float f; unsigned u; } v; v.f = f;
    unsigned r = (v.u + 0x7FFFu + ((v.u >> 16) & 1u)) >> 16;   // RNE
    return (short)r;
}
__device__ inline float bf2f(unsigned short u) {
    union { unsigned u; float f; } r; r.u = (unsigned)u << 16; return r.f;
}

// ---- 1. radix partition into padded buckets: bco[b*CAP+i] = (s<<8)|(d&255)

__global__ __launch_bounds__(256) void scat7_kernel(const int* __restrict__ src,
                                                    const int* __restrict__ dst,
                                                    int* __restrict__ bcursor,
                                                    unsigned* __restrict__ bco, int E) {
    __shared__ int h[NBUCK_MAX], h2[NBUCK_MAX], base[NBUCK_MAX];
    int t = threadIdx.x;
    h[t] = 0; h[t + 256] = 0; h2[t] = 0; h2[t + 256] = 0;
    __syncthreads();
    int cb = blockIdx.x * 2048;
    int d[8], s[8];
    bool m[8];
    #pragma unroll
    for (int u = 0; u < 8; ++u) {
        int e = cb + u * 256 + t;
        m[u] = e < E;
        d[u] = m[u] ? __builtin_nontemporal_load(dst + e) : 0;
        s[u] = m[u] ? __builtin_nontemporal_load(src + e) : 0;
        if (m[u]) atomicAdd(&h[d[u] >> 8], 1);
    }
    __syncthreads();
    #pragma unroll
    for (int b = 0; b < 2; ++b) {
        int bb = t + b * 256;
        if (h[bb]) base[bb] = bb * CAP + atomicAdd(&bcursor[bb], h[bb]);
    }
    __syncthreads();
    #pragma unroll
    for (int u = 0; u < 8; ++u) {
        if (m[u]) {
            int b = d[u] >> 8;
            int lp = atomicAdd(&h2[b], 1);
            bco[base[b] + lp] = ((unsigned)s[u] << 8) | (unsigned)(d[u] & 255);
        }
    }
}

// ---- 2. per-bucket counting sort -> rowinfo{beg,cnt,dinv}, dinv, csr_src --

__global__ __launch_bounds__(256) void sortb3_kernel(const unsigned* __restrict__ bco,
                                                     const int* __restrict__ bcursor,
                                                     int4* __restrict__ rowinfo,
                                                     float* __restrict__ dinv,
                                                     int* __restrict__ csr_src, int N) {
    __shared__ int deg[256], ex[256], sc[256];
    int b = blockIdx.x, t = threadIdx.x;
    int lo = b * 256;
    int nn = N - lo; if (nn > 256) nn = 256;
    int ebeg = b * CAP;
    int ecnt = bcursor[b];

    deg[t] = 0;
    __syncthreads();
    for (int i = t; i < ecnt; i += 256)
        atomicAdd(&deg[bco[ebeg + i] & 255u], 1);
    __syncthreads();
    int v = deg[t];
    sc[t] = v;
    __syncthreads();
    for (int off = 1; off < 256; off <<= 1) {
        int u = (t >= off) ? sc[t - off] : 0;
        __syncthreads();
        sc[t] += u;
        __syncthreads();
    }
    int ext = sc[t] - v;            // exclusive prefix
    ex[t] = ext;
    if (t < nn) {
        float di = rsqrtf((float)(v + 1));          // +1 self-loop
        int4 ri;
        ri.x = ebeg + ext;
        ri.y = v;
        ri.z = __float_as_int(di);
        ri.w = 0;
        rowinfo[lo + t] = ri;
        dinv[lo + t]    = di;
    }
    __syncthreads();
    for (int i = t; i < ecnt; i += 256) {
        unsigned e = bco[ebeg + i];
        int p = atomicAdd(&ex[e & 255u], 1);
        csr_src[ebeg + p] = (int)(e >> 8);
    }
}

// ---- W -> MFMA fragment pack ---------------------------------------------

__global__ void wfrag_kernel(const float* __restrict__ W, short* __restrict__ wfrag) {
    int i = blockIdx.x * blockDim.x + threadIdx.x;
    if (i >= 16 * 3 * 64) return;
    int kc = i / 192, rem = i % 192, tile = rem / 64, lane = rem % 64;
    int c = tile * 16 + (lane & 15);
    int kbase = kc * 32 + ((lane >> 4) << 3);
    bf16x8 out;
    #pragma unroll
    for (int j = 0; j < 8; ++j) {
        float v = (c < NCLS) ? W[(size_t)c * NFEAT + kbase + j] : 0.f;
        out[j] = f2bf(v);
    }
    *(bf16x8*)(wfrag + (size_t)i * 8) = out;
}

// ---- z' = dinv.(x @ W^T) via MFMA bf16, split-plane output ---------------

__global__ __launch_bounds__(512) void gemm6_kernel(const float* __restrict__ x,
                                                    const short* __restrict__ wfrag,
                                                    const float* __restrict__ dinv,
                                                    unsigned short* __restrict__ zA,
                                                    unsigned short* __restrict__ zB, int n) {
    __shared__ short xl[2][128 * 40];
    int t = threadIdx.x;
    int w = t >> 6, l = t & 63;
    int lrow = l & 15, lk = l >> 4;
    int rowBase = blockIdx.x * 128;
    int srow = t >> 2, skq = t & 3;
    f32x4 acc0 = {0.f, 0.f, 0.f, 0.f}, acc1 = acc0, acc2 = acc0;
    const float* xrow = x + (size_t)(rowBase + srow) * NFEAT + skq * 8;
    bool srOK = (rowBase + srow) < n;
    int aoff = (w * 16 + lrow) * 40 + lk * 8;
    int doff = srow * 40 + skq * 8;

    {   // prologue: stage kc=0
        float4 v0 = make_float4(0.f, 0.f, 0.f, 0.f), v1 = v0;
        if (srOK) { const float4* xp = (const float4*)xrow; v0 = xp[0]; v1 = xp[1]; }
        bf16x8 bv;
        bv[0] = f2bf(v0.x); bv[1] = f2bf(v0.y); bv[2] = f2bf(v0.z); bv[3] = f2bf(v0.w);
        bv[4] = f2bf(v1.x); bv[5] = f2bf(v1.y); bv[6] = f2bf(v1.z); bv[7] = f2bf(v1.w);
        *(bf16x8*)&xl[0][doff] = bv;
    }
    __syncthreads();

    for (int kc = 0; kc < 16; ++kc) {
        int cur = kc & 1;
        float4 v0 = make_float4(0.f, 0.f, 0.f, 0.f), v1 = v0;
        if (kc < 15 && srOK) {                      // issue next chunk early
            const float4* xp = (const float4*)(xrow + (kc + 1) * 32);
            v0 = xp[0]; v1 = xp[1];
        }
        bf16x8 af = *(const bf16x8*)&xl[cur][aoff];
        const bf16x8* wf = (const bf16x8*)(wfrag + (size_t)kc * 3 * 64 * 8);
        bf16x8 b0 = wf[l];
        bf16x8 b1 = wf[64 + l];
        bf16x8 b2 = wf[128 + l];
        acc0 = __builtin_amdgcn_mfma_f32_16x16x32_bf16(af, b0, acc0, 0, 0, 0);
        acc1 = __builtin_amdgcn_mfma_f32_16x16x32_bf16(af, b1, acc1, 0, 0, 0);
        acc2 = __builtin_amdgcn_mfma_f32_16x16x32_bf16(af, b2, acc2, 0, 0, 0);
        if (kc < 15) {
            bf16x8 bv;
            bv[0] = f2bf(v0.x); bv[1] = f2bf(v0.y); bv[2] = f2bf(v0.z); bv[3] = f2bf(v0.w);
            bv[4] = f2bf(v1.x); bv[5] = f2bf(v1.y); bv[6] = f2bf(v1.z); bv[7] = f2bf(v1.w);
            *(bf16x8*)&xl[cur ^ 1][doff] = bv;
            __syncthreads();
        }
    }
    int r0 = rowBase + w * 16 + lk * 4;    // C/D: col=lane&15, row=(lane>>4)*4+reg
    #pragma unroll
    for (int reg = 0; reg < 4; ++reg) {
        int row = r0 + reg;
        if (row < n) {
            float sc = dinv[row];                   // pre-scale: z' = dinv*z
            unsigned short* zpA = zA + (size_t)row * 32;
            zpA[lrow]      = (unsigned short)f2bf(acc0[reg] * sc);
            zpA[16 + lrow] = (unsigned short)f2bf(acc1[reg] * sc);
            if (lrow < 8) zB[(size_t)row * 8 + lrow] = (unsigned short)f2bf(acc2[reg] * sc);
        }
    }
}

// ---- unweighted pull-SpMM over split planes ------------------------------
// lane<32 reads plane A (1 line/edge); lanes 32..39 read plane B (L2-hot).

template <bool FINAL>
__global__ __launch_bounds__(256) void spmm7_kernel(const unsigned short* __restrict__ inA,
                                                    const unsigned short* __restrict__ inB,
                                                    const int4* __restrict__ rowinfo,
                                                    const int* __restrict__ csr,
                                                    const float* __restrict__ bias,
                                                    unsigned short* __restrict__ outA,
                                                    unsigned short* __restrict__ outB,
                                                    float* __restrict__ outF, int n) {
    int wv = (int)((blockIdx.x * (size_t)blockDim.x + threadIdx.x) >> 6);
    wv = __builtin_amdgcn_readfirstlane(wv);        // force SGPR (uniform)
    if (wv >= n) return;
    int lane = threadIdx.x & 63;
    bool lact = lane < NCLS;
    bool isA  = lane < 32;

    int4 ri = rowinfo[wv];                          // s_load_dwordx4
    int beg = ri.x, tot = ri.y;
    float dd = __int_as_float(ri.z);

    float a = 0.f;
    {   // self term, split read
        const unsigned short* rp = isA ? (inA + (size_t)wv * 32)
                                       : (inB + (size_t)wv * 8 - 32);
        if (lact) a = bf2f(rp[lane]);
    }

    int j = 0;
    for (; j + 4 <= tot; j += 4) {
        int s0 = csr[beg + j];
        int s1 = csr[beg + j + 1];
        int s2 = csr[beg + j + 2];
        int s3 = csr[beg + j + 3];
        const unsigned short* r0 = isA ? (inA + (size_t)s0 * 32) : (inB + (size_t)s0 * 8 - 32);
        const unsigned short* r1 = isA ? (inA + (size_t)s1 * 32) : (inB + (size_t)s1 * 8 - 32);
        const unsigned short* r2 = isA ? (inA + (size_t)s2 * 32) : (inB + (size_t)s2 * 8 - 32);
        const unsigned short* r3 = isA ? (inA + (size_t)s3 * 32) : (inB + (size_t)s3 * 8 - 32);
        if (lact) {
            float v0 = bf2f(r0[lane]);
            float v1 = bf2f(r1[lane]);
            float v2 = bf2f(r2[lane]);
            float v3 = bf2f(r3[lane]);
            a += v0; a += v1; a += v2; a += v3;
        }
    }
    for (; j < tot; ++j) {
        int s = csr[beg + j];
        const unsigned short* rp = isA ? (inA + (size_t)s * 32) : (inB + (size_t)s * 8 - 32);
        if (lact) a += bf2f(rp[lane]);
    }

    if (!FINAL) {
        if (lact) {
            unsigned short o = (unsigned short)f2bf(a * dd * dd);
            if (isA) outA[(size_t)wv * 32 + lane] = o;
            else     outB[(size_t)wv * 8 + lane - 32] = o;
        }
    } else {
        float v = lact ? a * dd + bias[lane] : -INFINITY;
        float m = v;
        #pragma unroll
        for (int off = 32; off; off >>= 1) m = fmaxf(m, __shfl_xor(m, off, 64));
        float e = lact ? expf(v - m) : 0.f;
        float s = e;
        #pragma unroll
        for (int off = 32; off; off >>= 1) s += __shfl_xor(s, off, 64);
        float lse = logf(s);
        if (lact) outF[(size_t)wv * NCLS + lane] = v - m - lse;
    }
}

// ---- driver -------------------------------------------------------------

extern "C" void kernel_launch(void* const* d_in, const int* in_sizes, int n_in,
                              void* d_out, int out_size, void* d_ws, size_t ws_size,
                              hipStream_t stream) {
    const float* x  = (const float*)d_in[0];
    const int*   ei = (const int*)d_in[1];
    const float* W  = (const float*)d_in[2];
    const float* b  = (const float*)d_in[3];

    const int N = in_sizes[0] / NFEAT;
    const int E = in_sizes[1] / 2;
    const int* src = ei;
    const int* dst = ei + E;
    const int nbuck = (N + 255) >> 8;      // 391

    char* p = (char*)d_ws;
    auto alloc = [&](size_t bytes) -> void* {
        void* r = (void*)p;
        p += (bytes + 255) & ~(size_t)255;
        return r;
    };
    int*      bcursor = (int*)     alloc((size_t)NBUCK_MAX * 4);
    int4*     rowinfo = (int4*)    alloc((size_t)N * 16);
    float*    dinv    = (float*)   alloc((size_t)N * 4);
    unsigned* bco     = (unsigned*)alloc((size_t)nbuck * CAP * 4 + 64);
    int*      csr_src = (int*)     alloc((size_t)nbuck * CAP * 4 + 64);
    short*    wfrag   = (short*)   alloc((size_t)16 * 3 * 64 * 8 * 2);
    unsigned short* zA  = (unsigned short*)alloc((size_t)N * 32 * 2);   // 6.4MB
    unsigned short* zB  = (unsigned short*)alloc((size_t)N * 8 * 2);    // 1.6MB
    unsigned short* h1A = (unsigned short*)alloc((size_t)N * 32 * 2);
    unsigned short* h1B = (unsigned short*)alloc((size_t)N * 8 * 2);

    hipMemsetAsync(bcursor, 0, (size_t)NBUCK_MAX * 4, stream);

    int cb = (E + 2047) / 2048;
    scat7_kernel<<<cb, 256, 0, stream>>>(src, dst, bcursor, bco, E);
    sortb3_kernel<<<nbuck, 256, 0, stream>>>(bco, bcursor, rowinfo, dinv, csr_src, N);

    wfrag_kernel<<<12, 256, 0, stream>>>(W, wfrag);
    gemm6_kernel<<<(N + 127) / 128, 512, 0, stream>>>(x, wfrag, dinv, zA, zB, N);

    int wb = (int)(((size_t)N * 64 + 255) / 256);
    spmm7_kernel<false><<<wb, 256, 0, stream>>>(zA, zB, rowinfo, csr_src, b,
                                                h1A, h1B, nullptr, N);
    spmm7_kernel<true ><<<wb, 256, 0, stream>>>(h1A, h1B, rowinfo, csr_src, b,
                                                nullptr, nullptr, (float*)d_out, N);
}

// Round 14
// 302.125 us; speedup vs baseline: 5.4473x; 1.1356x over previous
//
#include <hip/hip_runtime.h>
#include <hip/hip_bf16.h>
#include <math.h>

// SGC: out = log_softmax( (A_norm^2 x) W^T + b )
// (A^2 x) W^T == A^2 (x W^T): propagate 40-dim. Weight factorization:
// z' = dinv.z; pass1 = dd^2*sum (bf16); pass2 = dd*sum + b -> log_softmax.
// SPLIT-PLANE features: plane A = classes 0..31 (64B rows = 1 line/gather),
// plane B = classes 32..39 (16B rows, 1.6MB L2-resident). R14 fix vs R13:
// per-lane base/stride hoisted OUT of the edge loop (R13's per-edge pointer
// ternary doubled VALU and hid the byte win -> 343us).
// CSR build: padded radix buckets of 256 nodes + counting sort.

#define NFEAT 512
#define NCLS  40
#define NBUCK_MAX 512          // buckets = ceil(N/256); N=100000 -> 391
#define CAP   9728             // bucket capacity: mean 8192 + ~17 sigma

typedef __attribute__((ext_vector_type(8))) short bf16x8;
typedef __attribute__((ext_vector_type(4))) float f32x4;

__device__ inline short f2bf(float f) {
    union { float f; unsigned u; } v; v.f = f;
    unsigned r = (v.u + 0x7FFFu + ((v.u >> 16) & 1u)) >> 16;   // RNE
    return (short)r;
}
__device__ inline float bf2f(unsigned short u) {
    union { unsigned u; float f; } r; r.u = (unsigned)u << 16; return r.f;
}

// ---- 1. radix partition into padded buckets: bco[b*CAP+i] = (s<<8)|(d&255)

__global__ __launch_bounds__(256) void scat7_kernel(const int* __restrict__ src,
                                                    const int* __restrict__ dst,
                                                    int* __restrict__ bcursor,
                                                    unsigned* __restrict__ bco, int E) {
    __shared__ int h[NBUCK_MAX], h2[NBUCK_MAX], base[NBUCK_MAX];
    int t = threadIdx.x;
    h[t] = 0; h[t + 256] = 0; h2[t] = 0; h2[t + 256] = 0;
    __syncthreads();
    int cb = blockIdx.x * 2048;
    int d[8], s[8];
    bool m[8];
    #pragma unroll
    for (int u = 0; u < 8; ++u) {
        int e = cb + u * 256 + t;
        m[u] = e < E;
        d[u] = m[u] ? __builtin_nontemporal_load(dst + e) : 0;
        s[u] = m[u] ? __builtin_nontemporal_load(src + e) : 0;
        if (m[u]) atomicAdd(&h[d[u] >> 8], 1);
    }
    __syncthreads();
    #pragma unroll
    for (int b = 0; b < 2; ++b) {
        int bb = t + b * 256;
        if (h[bb]) base[bb] = bb * CAP + atomicAdd(&bcursor[bb], h[bb]);
    }
    __syncthreads();
    #pragma unroll
    for (int u = 0; u < 8; ++u) {
        if (m[u]) {
            int b = d[u] >> 8;
            int lp = atomicAdd(&h2[b], 1);
            bco[base[b] + lp] = ((unsigned)s[u] << 8) | (unsigned)(d[u] & 255);
        }
    }
}

// ---- 2. per-bucket counting sort -> rowinfo{beg,cnt,dinv}, dinv, csr_src --

__global__ __launch_bounds__(256) void sortb3_kernel(const unsigned* __restrict__ bco,
                                                     const int* __restrict__ bcursor,
                                                     int4* __restrict__ rowinfo,
                                                     float* __restrict__ dinv,
                                                     int* __restrict__ csr_src, int N) {
    __shared__ int deg[256], ex[256], sc[256];
    int b = blockIdx.x, t = threadIdx.x;
    int lo = b * 256;
    int nn = N - lo; if (nn > 256) nn = 256;
    int ebeg = b * CAP;
    int ecnt = bcursor[b];

    deg[t] = 0;
    __syncthreads();
    for (int i = t; i < ecnt; i += 256)
        atomicAdd(&deg[bco[ebeg + i] & 255u], 1);
    __syncthreads();
    int v = deg[t];
    sc[t] = v;
    __syncthreads();
    for (int off = 1; off < 256; off <<= 1) {
        int u = (t >= off) ? sc[t - off] : 0;
        __syncthreads();
        sc[t] += u;
        __syncthreads();
    }
    int ext = sc[t] - v;            // exclusive prefix
    ex[t] = ext;
    if (t < nn) {
        float di = rsqrtf((float)(v + 1));          // +1 self-loop
        int4 ri;
        ri.x = ebeg + ext;
        ri.y = v;
        ri.z = __float_as_int(di);
        ri.w = 0;
        rowinfo[lo + t] = ri;
        dinv[lo + t]    = di;
    }
    __syncthreads();
    for (int i = t; i < ecnt; i += 256) {
        unsigned e = bco[ebeg + i];
        int p = atomicAdd(&ex[e & 255u], 1);
        csr_src[ebeg + p] = (int)(e >> 8);
    }
}

// ---- W -> MFMA fragment pack ---------------------------------------------

__global__ void wfrag_kernel(const float* __restrict__ W, short* __restrict__ wfrag) {
    int i = blockIdx.x * blockDim.x + threadIdx.x;
    if (i >= 16 * 3 * 64) return;
    int kc = i / 192, rem = i % 192, tile = rem / 64, lane = rem % 64;
    int c = tile * 16 + (lane & 15);
    int kbase = kc * 32 + ((lane >> 4) << 3);
    bf16x8 out;
    #pragma unroll
    for (int j = 0; j < 8; ++j) {
        float v = (c < NCLS) ? W[(size_t)c * NFEAT + kbase + j] : 0.f;
        out[j] = f2bf(v);
    }
    *(bf16x8*)(wfrag + (size_t)i * 8) = out;
}

// ---- z' = dinv.(x @ W^T) via MFMA bf16, split-plane output ---------------

__global__ __launch_bounds__(512) void gemm6_kernel(const float* __restrict__ x,
                                                    const short* __restrict__ wfrag,
                                                    const float* __restrict__ dinv,
                                                    unsigned short* __restrict__ zA,
                                                    unsigned short* __restrict__ zB, int n) {
    __shared__ short xl[2][128 * 40];
    int t = threadIdx.x;
    int w = t >> 6, l = t & 63;
    int lrow = l & 15, lk = l >> 4;
    int rowBase = blockIdx.x * 128;
    int srow = t >> 2, skq = t & 3;
    f32x4 acc0 = {0.f, 0.f, 0.f, 0.f}, acc1 = acc0, acc2 = acc0;
    const float* xrow = x + (size_t)(rowBase + srow) * NFEAT + skq * 8;
    bool srOK = (rowBase + srow) < n;
    int aoff = (w * 16 + lrow) * 40 + lk * 8;
    int doff = srow * 40 + skq * 8;

    {   // prologue: stage kc=0
        float4 v0 = make_float4(0.f, 0.f, 0.f, 0.f), v1 = v0;
        if (srOK) { const float4* xp = (const float4*)xrow; v0 = xp[0]; v1 = xp[1]; }
        bf16x8 bv;
        bv[0] = f2bf(v0.x); bv[1] = f2bf(v0.y); bv[2] = f2bf(v0.z); bv[3] = f2bf(v0.w);
        bv[4] = f2bf(v1.x); bv[5] = f2bf(v1.y); bv[6] = f2bf(v1.z); bv[7] = f2bf(v1.w);
        *(bf16x8*)&xl[0][doff] = bv;
    }
    __syncthreads();

    for (int kc = 0; kc < 16; ++kc) {
        int cur = kc & 1;
        float4 v0 = make_float4(0.f, 0.f, 0.f, 0.f), v1 = v0;
        if (kc < 15 && srOK) {                      // issue next chunk early
            const float4* xp = (const float4*)(xrow + (kc + 1) * 32);
            v0 = xp[0]; v1 = xp[1];
        }
        bf16x8 af = *(const bf16x8*)&xl[cur][aoff];
        const bf16x8* wf = (const bf16x8*)(wfrag + (size_t)kc * 3 * 64 * 8);
        bf16x8 b0 = wf[l];
        bf16x8 b1 = wf[64 + l];
        bf16x8 b2 = wf[128 + l];
        acc0 = __builtin_amdgcn_mfma_f32_16x16x32_bf16(af, b0, acc0, 0, 0, 0);
        acc1 = __builtin_amdgcn_mfma_f32_16x16x32_bf16(af, b1, acc1, 0, 0, 0);
        acc2 = __builtin_amdgcn_mfma_f32_16x16x32_bf16(af, b2, acc2, 0, 0, 0);
        if (kc < 15) {
            bf16x8 bv;
            bv[0] = f2bf(v0.x); bv[1] = f2bf(v0.y); bv[2] = f2bf(v0.z); bv[3] = f2bf(v0.w);
            bv[4] = f2bf(v1.x); bv[5] = f2bf(v1.y); bv[6] = f2bf(v1.z); bv[7] = f2bf(v1.w);
            *(bf16x8*)&xl[cur ^ 1][doff] = bv;
            __syncthreads();
        }
    }
    int r0 = rowBase + w * 16 + lk * 4;    // C/D: col=lane&15, row=(lane>>4)*4+reg
    #pragma unroll
    for (int reg = 0; reg < 4; ++reg) {
        int row = r0 + reg;
        if (row < n) {
            float sc = dinv[row];                   // pre-scale: z' = dinv*z
            unsigned short* zpA = zA + (size_t)row * 32;
            zpA[lrow]      = (unsigned short)f2bf(acc0[reg] * sc);
            zpA[16 + lrow] = (unsigned short)f2bf(acc1[reg] * sc);
            if (lrow < 8) zB[(size_t)row * 8 + lrow] = (unsigned short)f2bf(acc2[reg] * sc);
        }
    }
}

// ---- unweighted pull-SpMM over split planes, hoisted per-lane addressing --
// lane<32: plane A (row stride 64B, 1 line/edge). lanes 32..39: plane B
// (stride 16B, L2-hot). Per edge: addr = lane_base + (s << lane_shift).

template <bool FINAL>
__global__ __launch_bounds__(256) void spmm8_kernel(const unsigned short* __restrict__ inA,
                                                    const unsigned short* __restrict__ inB,
                                                    const int4* __restrict__ rowinfo,
                                                    const int* __restrict__ csr,
                                                    const float* __restrict__ bias,
                                                    unsigned short* __restrict__ outA,
                                                    unsigned short* __restrict__ outB,
                                                    float* __restrict__ outF, int n) {
    int wv = (int)((blockIdx.x * (size_t)blockDim.x + threadIdx.x) >> 6);
    wv = __builtin_amdgcn_readfirstlane(wv);        // force SGPR (uniform)
    if (wv >= n) return;
    int lane = threadIdx.x & 63;
    bool lact = lane < NCLS;
    bool isA  = lane < 32;

    // loop-invariant per-lane gather base + shift
    const char* lane_base = isA ? ((const char*)inA + lane * 2)
                                : ((const char*)inB + (lane - 32) * 2);
    unsigned lane_sh = isA ? 6u : 4u;

    int4 ri = rowinfo[wv];                          // s_load_dwordx4
    int beg = ri.x, tot = ri.y;
    float dd = __int_as_float(ri.z);

    float a = 0.f;
    if (lact) a = bf2f(*(const unsigned short*)(lane_base + ((size_t)wv << lane_sh)));

    int j = 0;
    for (; j + 4 <= tot; j += 4) {
        int s0 = csr[beg + j];
        int s1 = csr[beg + j + 1];
        int s2 = csr[beg + j + 2];
        int s3 = csr[beg + j + 3];
        if (lact) {
            float v0 = bf2f(*(const unsigned short*)(lane_base + ((size_t)s0 << lane_sh)));
            float v1 = bf2f(*(const unsigned short*)(lane_base + ((size_t)s1 << lane_sh)));
            float v2 = bf2f(*(const unsigned short*)(lane_base + ((size_t)s2 << lane_sh)));
            float v3 = bf2f(*(const unsigned short*)(lane_base + ((size_t)s3 << lane_sh)));
            a += v0; a += v1; a += v2; a += v3;
        }
    }
    for (; j < tot; ++j) {
        int s = csr[beg + j];
        if (lact) a += bf2f(*(const unsigned short*)(lane_base + ((size_t)s << lane_sh)));
    }

    if (!FINAL) {
        if (lact) {
            unsigned short o = (unsigned short)f2bf(a * dd * dd);
            if (isA) outA[(size_t)wv * 32 + lane] = o;
            else     outB[(size_t)wv * 8 + lane - 32] = o;
        }
    } else {
        float v = lact ? a * dd + bias[lane] : -INFINITY;
        float m = v;
        #pragma unroll
        for (int off = 32; off; off >>= 1) m = fmaxf(m, __shfl_xor(m, off, 64));
        float e = lact ? expf(v - m) : 0.f;
        float s = e;
        #pragma unroll
        for (int off = 32; off; off >>= 1) s += __shfl_xor(s, off, 64);
        float lse = logf(s);
        if (lact) outF[(size_t)wv * NCLS + lane] = v - m - lse;
    }
}

// ---- driver -------------------------------------------------------------

extern "C" void kernel_launch(void* const* d_in, const int* in_sizes, int n_in,
                              void* d_out, int out_size, void* d_ws, size_t ws_size,
                              hipStream_t stream) {
    const float* x  = (const float*)d_in[0];
    const int*   ei = (const int*)d_in[1];
    const float* W  = (const float*)d_in[2];
    const float* b  = (const float*)d_in[3];

    const int N = in_sizes[0] / NFEAT;
    const int E = in_sizes[1] / 2;
    const int* src = ei;
    const int* dst = ei + E;
    const int nbuck = (N + 255) >> 8;      // 391

    char* p = (char*)d_ws;
    auto alloc = [&](size_t bytes) -> void* {
        void* r = (void*)p;
        p += (bytes + 255) & ~(size_t)255;
        return r;
    };
    int*      bcursor = (int*)     alloc((size_t)NBUCK_MAX * 4);
    int4*     rowinfo = (int4*)    alloc((size_t)N * 16);
    float*    dinv    = (float*)   alloc((size_t)N * 4);
    unsigned* bco     = (unsigned*)alloc((size_t)nbuck * CAP * 4 + 64);
    int*      csr_src = (int*)     alloc((size_t)nbuck * CAP * 4 + 64);
    short*    wfrag   = (short*)   alloc((size_t)16 * 3 * 64 * 8 * 2);
    unsigned short* zA  = (unsigned short*)alloc((size_t)N * 32 * 2);   // 6.4MB
    unsigned short* zB  = (unsigned short*)alloc((size_t)N * 8 * 2);    // 1.6MB
    unsigned short* h1A = (unsigned short*)alloc((size_t)N * 32 * 2);
    unsigned short* h1B = (unsigned short*)alloc((size_t)N * 8 * 2);

    hipMemsetAsync(bcursor, 0, (size_t)NBUCK_MAX * 4, stream);

    int cb = (E + 2047) / 2048;
    scat7_kernel<<<cb, 256, 0, stream>>>(src, dst, bcursor, bco, E);
    sortb3_kernel<<<nbuck, 256, 0, stream>>>(bco, bcursor, rowinfo, dinv, csr_src, N);

    wfrag_kernel<<<12, 256, 0, stream>>>(W, wfrag);
    gemm6_kernel<<<(N + 127) / 128, 512, 0, stream>>>(x, wfrag, dinv, zA, zB, N);

    int wb = (int)(((size_t)N * 64 + 255) / 256);
    spmm8_kernel<false><<<wb, 256, 0, stream>>>(zA, zB, rowinfo, csr_src, b,
                                                h1A, h1B, nullptr, N);
    spmm8_kernel<true ><<<wb, 256, 0, stream>>>(h1A, h1B, rowinfo, csr_src, b,
                                                nullptr, nullptr, (float*)d_out, N);
}

// Round 15
// 260.813 us; speedup vs baseline: 6.3101x; 1.1584x over previous
//
#include <hip/hip_runtime.h>
#include <hip/hip_bf16.h>
#include <math.h>

// SGC: out = log_softmax( (A_norm^2 x) W^T + b )
// (A^2 x) W^T == A^2 (x W^T): propagate 40-dim. Weight factorization:
// z' = dinv.z; pass1 = dd^2*sum (bf16); pass2 = dd*sum + b -> log_softmax.
// SPLIT-PLANE features: A = classes 0..31 (64B rows, 1 line/edge),
// B = classes 32..39 (16B rows, L2-hot). R15: spmm inner loop is a 16-deep
// gather batch (load 16 idx -> issue 16 independent gathers -> 16 adds):
// the phase is VMEM-latency x outstanding-requests bound (R12/R14 evidence:
// byte cuts moved nothing, VALUBusy 39%), so the lever is MLP depth.
// CSR build: padded radix buckets of 256 nodes + counting sort.

#define NFEAT 512
#define NCLS  40
#define NBUCK_MAX 512          // buckets = ceil(N/256); N=100000 -> 391
#define CAP   9728             // bucket capacity: mean 8192 + ~17 sigma

typedef __attribute__((ext_vector_type(8))) short bf16x8;
typedef __attribute__((ext_vector_type(4))) float f32x4;

__device__ inline short f2bf(float f) {
    union { float f; unsigned u; } v; v.f = f;
    unsigned r = (v.u + 0x7FFFu + ((v.u >> 16) & 1u)) >> 16;   // RNE
    return (short)r;
}
__device__ inline float bf2f(unsigned short u) {
    union { unsigned u; float f; } r; r.u = (unsigned)u << 16; return r.f;
}

// ---- 1. radix partition into padded buckets: bco[b*CAP+i] = (s<<8)|(d&255)

__global__ __launch_bounds__(256) void scat7_kernel(const int* __restrict__ src,
                                                    const int* __restrict__ dst,
                                                    int* __restrict__ bcursor,
                                                    unsigned* __restrict__ bco, int E) {
    __shared__ int h[NBUCK_MAX], h2[NBUCK_MAX], base[NBUCK_MAX];
    int t = threadIdx.x;
    h[t] = 0; h[t + 256] = 0; h2[t] = 0; h2[t + 256] = 0;
    __syncthreads();
    int cb = blockIdx.x * 2048;
    int d[8], s[8];
    bool m[8];
    #pragma unroll
    for (int u = 0; u < 8; ++u) {
        int e = cb + u * 256 + t;
        m[u] = e < E;
        d[u] = m[u] ? __builtin_nontemporal_load(dst + e) : 0;
        s[u] = m[u] ? __builtin_nontemporal_load(src + e) : 0;
        if (m[u]) atomicAdd(&h[d[u] >> 8], 1);
    }
    __syncthreads();
    #pragma unroll
    for (int b = 0; b < 2; ++b) {
        int bb = t + b * 256;
        if (h[bb]) base[bb] = bb * CAP + atomicAdd(&bcursor[bb], h[bb]);
    }
    __syncthreads();
    #pragma unroll
    for (int u = 0; u < 8; ++u) {
        if (m[u]) {
            int b = d[u] >> 8;
            int lp = atomicAdd(&h2[b], 1);
            bco[base[b] + lp] = ((unsigned)s[u] << 8) | (unsigned)(d[u] & 255);
        }
    }
}

// ---- 2. per-bucket counting sort -> rowinfo{beg,cnt,dinv}, dinv, csr_src --

__global__ __launch_bounds__(256) void sortb3_kernel(const unsigned* __restrict__ bco,
                                                     const int* __restrict__ bcursor,
                                                     int4* __restrict__ rowinfo,
                                                     float* __restrict__ dinv,
                                                     int* __restrict__ csr_src, int N) {
    __shared__ int deg[256], ex[256], sc[256];
    int b = blockIdx.x, t = threadIdx.x;
    int lo = b * 256;
    int nn = N - lo; if (nn > 256) nn = 256;
    int ebeg = b * CAP;
    int ecnt = bcursor[b];

    deg[t] = 0;
    __syncthreads();
    for (int i = t; i < ecnt; i += 256)
        atomicAdd(&deg[bco[ebeg + i] & 255u], 1);
    __syncthreads();
    int v = deg[t];
    sc[t] = v;
    __syncthreads();
    for (int off = 1; off < 256; off <<= 1) {
        int u = (t >= off) ? sc[t - off] : 0;
        __syncthreads();
        sc[t] += u;
        __syncthreads();
    }
    int ext = sc[t] - v;            // exclusive prefix
    ex[t] = ext;
    if (t < nn) {
        float di = rsqrtf((float)(v + 1));          // +1 self-loop
        int4 ri;
        ri.x = ebeg + ext;
        ri.y = v;
        ri.z = __float_as_int(di);
        ri.w = 0;
        rowinfo[lo + t] = ri;
        dinv[lo + t]    = di;
    }
    __syncthreads();
    for (int i = t; i < ecnt; i += 256) {
        unsigned e = bco[ebeg + i];
        int p = atomicAdd(&ex[e & 255u], 1);
        csr_src[ebeg + p] = (int)(e >> 8);
    }
}

// ---- W -> MFMA fragment pack ---------------------------------------------

__global__ void wfrag_kernel(const float* __restrict__ W, short* __restrict__ wfrag) {
    int i = blockIdx.x * blockDim.x + threadIdx.x;
    if (i >= 16 * 3 * 64) return;
    int kc = i / 192, rem = i % 192, tile = rem / 64, lane = rem % 64;
    int c = tile * 16 + (lane & 15);
    int kbase = kc * 32 + ((lane >> 4) << 3);
    bf16x8 out;
    #pragma unroll
    for (int j = 0; j < 8; ++j) {
        float v = (c < NCLS) ? W[(size_t)c * NFEAT + kbase + j] : 0.f;
        out[j] = f2bf(v);
    }
    *(bf16x8*)(wfrag + (size_t)i * 8) = out;
}

// ---- z' = dinv.(x @ W^T) via MFMA bf16, split-plane output ---------------

__global__ __launch_bounds__(512) void gemm6_kernel(const float* __restrict__ x,
                                                    const short* __restrict__ wfrag,
                                                    const float* __restrict__ dinv,
                                                    unsigned short* __restrict__ zA,
                                                    unsigned short* __restrict__ zB, int n) {
    __shared__ short xl[2][128 * 40];
    int t = threadIdx.x;
    int w = t >> 6, l = t & 63;
    int lrow = l & 15, lk = l >> 4;
    int rowBase = blockIdx.x * 128;
    int srow = t >> 2, skq = t & 3;
    f32x4 acc0 = {0.f, 0.f, 0.f, 0.f}, acc1 = acc0, acc2 = acc0;
    const float* xrow = x + (size_t)(rowBase + srow) * NFEAT + skq * 8;
    bool srOK = (rowBase + srow) < n;
    int aoff = (w * 16 + lrow) * 40 + lk * 8;
    int doff = srow * 40 + skq * 8;

    {   // prologue: stage kc=0
        float4 v0 = make_float4(0.f, 0.f, 0.f, 0.f), v1 = v0;
        if (srOK) { const float4* xp = (const float4*)xrow; v0 = xp[0]; v1 = xp[1]; }
        bf16x8 bv;
        bv[0] = f2bf(v0.x); bv[1] = f2bf(v0.y); bv[2] = f2bf(v0.z); bv[3] = f2bf(v0.w);
        bv[4] = f2bf(v1.x); bv[5] = f2bf(v1.y); bv[6] = f2bf(v1.z); bv[7] = f2bf(v1.w);
        *(bf16x8*)&xl[0][doff] = bv;
    }
    __syncthreads();

    for (int kc = 0; kc < 16; ++kc) {
        int cur = kc & 1;
        float4 v0 = make_float4(0.f, 0.f, 0.f, 0.f), v1 = v0;
        if (kc < 15 && srOK) {                      // issue next chunk early
            const float4* xp = (const float4*)(xrow + (kc + 1) * 32);
            v0 = xp[0]; v1 = xp[1];
        }
        bf16x8 af = *(const bf16x8*)&xl[cur][aoff];
        const bf16x8* wf = (const bf16x8*)(wfrag + (size_t)kc * 3 * 64 * 8);
        bf16x8 b0 = wf[l];
        bf16x8 b1 = wf[64 + l];
        bf16x8 b2 = wf[128 + l];
        acc0 = __builtin_amdgcn_mfma_f32_16x16x32_bf16(af, b0, acc0, 0, 0, 0);
        acc1 = __builtin_amdgcn_mfma_f32_16x16x32_bf16(af, b1, acc1, 0, 0, 0);
        acc2 = __builtin_amdgcn_mfma_f32_16x16x32_bf16(af, b2, acc2, 0, 0, 0);
        if (kc < 15) {
            bf16x8 bv;
            bv[0] = f2bf(v0.x); bv[1] = f2bf(v0.y); bv[2] = f2bf(v0.z); bv[3] = f2bf(v0.w);
            bv[4] = f2bf(v1.x); bv[5] = f2bf(v1.y); bv[6] = f2bf(v1.z); bv[7] = f2bf(v1.w);
            *(bf16x8*)&xl[cur ^ 1][doff] = bv;
            __syncthreads();
        }
    }
    int r0 = rowBase + w * 16 + lk * 4;    // C/D: col=lane&15, row=(lane>>4)*4+reg
    #pragma unroll
    for (int reg = 0; reg < 4; ++reg) {
        int row = r0 + reg;
        if (row < n) {
            float sc = dinv[row];                   // pre-scale: z' = dinv*z
            unsigned short* zpA = zA + (size_t)row * 32;
            zpA[lrow]      = (unsigned short)f2bf(acc0[reg] * sc);
            zpA[16 + lrow] = (unsigned short)f2bf(acc1[reg] * sc);
            if (lrow < 8) zB[(size_t)row * 8 + lrow] = (unsigned short)f2bf(acc2[reg] * sc);
        }
    }
}

// ---- unweighted pull-SpMM, 16-deep gather batches (MLP) ------------------
// lane<32: plane A (stride 64B). lanes 32..39: plane B (stride 16B, L2-hot).
// addr = lane_base + (s << lane_sh); 16 indices -> 16 gathers in flight.

template <bool FINAL>
__global__ __launch_bounds__(256) void spmm9_kernel(const unsigned short* __restrict__ inA,
                                                    const unsigned short* __restrict__ inB,
                                                    const int4* __restrict__ rowinfo,
                                                    const int* __restrict__ csr,
                                                    const float* __restrict__ bias,
                                                    unsigned short* __restrict__ outA,
                                                    unsigned short* __restrict__ outB,
                                                    float* __restrict__ outF, int n) {
    int wv = (int)((blockIdx.x * (size_t)blockDim.x + threadIdx.x) >> 6);
    wv = __builtin_amdgcn_readfirstlane(wv);        // force SGPR (uniform)
    if (wv >= n) return;
    int lane = threadIdx.x & 63;
    bool lact = lane < NCLS;
    bool isA  = lane < 32;

    const char* lane_base = isA ? ((const char*)inA + lane * 2)
                                : ((const char*)inB + (lane - 32) * 2);
    unsigned lane_sh = isA ? 6u : 4u;

    int4 ri = rowinfo[wv];                          // s_load_dwordx4
    int beg = ri.x, tot = ri.y;
    float dd = __int_as_float(ri.z);

    float a = 0.f;
    if (lact) a = bf2f(*(const unsigned short*)(lane_base + ((size_t)wv << lane_sh)));

    int j = 0;
    for (; j + 16 <= tot; j += 16) {                // 16 gathers in flight
        int ss[16];
        #pragma unroll
        for (int u = 0; u < 16; ++u) ss[u] = csr[beg + j + u];
        if (lact) {
            float vv[16];
            #pragma unroll
            for (int u = 0; u < 16; ++u)
                vv[u] = bf2f(*(const unsigned short*)(lane_base + ((size_t)ss[u] << lane_sh)));
            #pragma unroll
            for (int u = 0; u < 16; ++u) a += vv[u];
        }
    }
    for (; j + 4 <= tot; j += 4) {
        int ss[4];
        #pragma unroll
        for (int u = 0; u < 4; ++u) ss[u] = csr[beg + j + u];
        if (lact) {
            float vv[4];
            #pragma unroll
            for (int u = 0; u < 4; ++u)
                vv[u] = bf2f(*(const unsigned short*)(lane_base + ((size_t)ss[u] << lane_sh)));
            #pragma unroll
            for (int u = 0; u < 4; ++u) a += vv[u];
        }
    }
    for (; j < tot; ++j) {
        int s = csr[beg + j];
        if (lact) a += bf2f(*(const unsigned short*)(lane_base + ((size_t)s << lane_sh)));
    }

    if (!FINAL) {
        if (lact) {
            unsigned short o = (unsigned short)f2bf(a * dd * dd);
            if (isA) outA[(size_t)wv * 32 + lane] = o;
            else     outB[(size_t)wv * 8 + lane - 32] = o;
        }
    } else {
        float v = lact ? a * dd + bias[lane] : -INFINITY;
        float m = v;
        #pragma unroll
        for (int off = 32; off; off >>= 1) m = fmaxf(m, __shfl_xor(m, off, 64));
        float e = lact ? expf(v - m) : 0.f;
        float s = e;
        #pragma unroll
        for (int off = 32; off; off >>= 1) s += __shfl_xor(s, off, 64);
        float lse = logf(s);
        if (lact) outF[(size_t)wv * NCLS + lane] = v - m - lse;
    }
}

// ---- driver -------------------------------------------------------------

extern "C" void kernel_launch(void* const* d_in, const int* in_sizes, int n_in,
                              void* d_out, int out_size, void* d_ws, size_t ws_size,
                              hipStream_t stream) {
    const float* x  = (const float*)d_in[0];
    const int*   ei = (const int*)d_in[1];
    const float* W  = (const float*)d_in[2];
    const float* b  = (const float*)d_in[3];

    const int N = in_sizes[0] / NFEAT;
    const int E = in_sizes[1] / 2;
    const int* src = ei;
    const int* dst = ei + E;
    const int nbuck = (N + 255) >> 8;      // 391

    char* p = (char*)d_ws;
    auto alloc = [&](size_t bytes) -> void* {
        void* r = (void*)p;
        p += (bytes + 255) & ~(size_t)255;
        return r;
    };
    int*      bcursor = (int*)     alloc((size_t)NBUCK_MAX * 4);
    int4*     rowinfo = (int4*)    alloc((size_t)N * 16);
    float*    dinv    = (float*)   alloc((size_t)N * 4);
    unsigned* bco     = (unsigned*)alloc((size_t)nbuck * CAP * 4 + 64);
    int*      csr_src = (int*)     alloc((size_t)nbuck * CAP * 4 + 64);
    short*    wfrag   = (short*)   alloc((size_t)16 * 3 * 64 * 8 * 2);
    unsigned short* zA  = (unsigned short*)alloc((size_t)N * 32 * 2);   // 6.4MB
    unsigned short* zB  = (unsigned short*)alloc((size_t)N * 8 * 2);    // 1.6MB
    unsigned short* h1A = (unsigned short*)alloc((size_t)N * 32 * 2);
    unsigned short* h1B = (unsigned short*)alloc((size_t)N * 8 * 2);

    hipMemsetAsync(bcursor, 0, (size_t)NBUCK_MAX * 4, stream);

    int cb = (E + 2047) / 2048;
    scat7_kernel<<<cb, 256, 0, stream>>>(src, dst, bcursor, bco, E);
    sortb3_kernel<<<nbuck, 256, 0, stream>>>(bco, bcursor, rowinfo, dinv, csr_src, N);

    wfrag_kernel<<<12, 256, 0, stream>>>(W, wfrag);
    gemm6_kernel<<<(N + 127) / 128, 512, 0, stream>>>(x, wfrag, dinv, zA, zB, N);

    int wb = (int)(((size_t)N * 64 + 255) / 256);
    spmm9_kernel<false><<<wb, 256, 0, stream>>>(zA, zB, rowinfo, csr_src, b,
                                                h1A, h1B, nullptr, N);
    spmm9_kernel<true ><<<wb, 256, 0, stream>>>(h1A, h1B, rowinfo, csr_src, b,
                                                nullptr, nullptr, (float*)d_out, N);
}